// Round 10
// baseline (423.022 us; speedup 1.0000x reference)
//
#include <hip/hip_runtime.h>

typedef __bf16 bf16x8 __attribute__((ext_vector_type(8)));
typedef float f32x4 __attribute__((ext_vector_type(4)));
typedef float f32x16 __attribute__((ext_vector_type(16)));
typedef unsigned short u16x4 __attribute__((ext_vector_type(4)));
typedef unsigned short u16x8 __attribute__((ext_vector_type(8)));

#define KP 2112   // padded K: 2080 + 32 = 33 * 64
#define NT 33     // K-tiles of 64

__device__ __forceinline__ unsigned short f2bf(float f) {
  unsigned int u = __builtin_bit_cast(unsigned int, f);
  u += 0x7FFFu + ((u >> 16) & 1u);   // round-to-nearest-even
  return (unsigned short)(u >> 16);
}

__device__ __forceinline__ bf16x8 ld_frag(const unsigned short* p) {
  return __builtin_bit_cast(bf16x8, *(const u16x8*)p);
}

#define MFMA16(a, b, c) __builtin_amdgcn_mfma_f32_16x16x32_bf16((a), (b), (c), 0, 0, 0)
#define MFMA32(a, b, c) __builtin_amdgcn_mfma_f32_32x32x16_bf16((a), (b), (c), 0, 0, 0)

// async global->LDS, 16B per lane (global_load_lds_dwordx4)
__device__ __forceinline__ void cp16(const void* g, void* l) {
  __builtin_amdgcn_global_load_lds(
      (const __attribute__((address_space(1))) unsigned int*)g,
      (__attribute__((address_space(3))) unsigned int*)l, 16, 0, 0);
}

// enter barrier with ds_reads in flight; drain after (reads were issued one
// phase earlier -> drain is cheap). sched_barrier is load-bearing (rule #18).
__device__ __forceinline__ void gate() {
  __builtin_amdgcn_s_barrier();
  asm volatile("s_waitcnt lgkmcnt(0)" ::: "memory");
  __builtin_amdgcn_sched_barrier(0);
}
__device__ __forceinline__ void close_bar() {
  asm volatile("" ::: "memory");
  __builtin_amdgcn_s_barrier();
}

#define VMWAIT(N) asm volatile("s_waitcnt vmcnt(" #N ")" ::: "memory")

// ---------------------------------------------------------------------------
// Coalesced triangular emit: 2112 u16 per matrix as u16x8 per thread (+ tail
// jobs on tid<8). (i,j) recovered analytically from flat idx p via sqrt+fixup.
// ---------------------------------------------------------------------------
__device__ __forceinline__ void emit_tri(const unsigned short* __restrict__ sK,
                                         unsigned short* __restrict__ dst,
                                         bool upper, int tid) {
#pragma unroll
  for (int jj = 0; jj < 2; ++jj) {
    if (jj == 1 && tid >= 8) break;
    const int p0 = (jj == 0) ? tid * 8 : 2048 + tid * 8;
    int i, j;
    if (upper) {
      // U_i = i*(129-i)/2 rows start; row i spans [U_i, U_{i+1}) len 64-i
      float s = sqrtf(4160.25f - 2.0f * (float)p0);
      i = (int)(64.5f - s);
      if (i < 0) i = 0;
      if (i > 63) i = 63;
      while (i > 0 && i * (129 - i) / 2 > p0) --i;
      while (i < 63 && (i + 1) * (128 - i) / 2 <= p0) ++i;
      j = i + (p0 - i * (129 - i) / 2);
    } else {
      // T_i = i*(i+1)/2; row i spans [T_i, T_{i+1}) len i+1
      float s = sqrtf(8.0f * (float)p0 + 1.0f);
      i = (int)((s - 1.0f) * 0.5f);
      if (i < 0) i = 0;
      if (i > 63) i = 63;
      while (i > 0 && i * (i + 1) / 2 > p0) --i;
      while (i < 63 && (i + 1) * (i + 2) / 2 <= p0) ++i;
      j = p0 - i * (i + 1) / 2;
    }
    u16x8 o;
#pragma unroll
    for (int e = 0; e < 8; ++e) {
      const int p = p0 + e;
      o[e] = (p < 2080 && i < 64) ? sK[i * 64 + j] : (unsigned short)0;
      if (upper) { if (++j > 63) { ++i; j = i; } }
      else       { if (++j > i)  { ++i; j = 0; } }
    }
    *(u16x8*)(dst + p0) = o;
  }
}

// ---------------------------------------------------------------------------
// Fused prep: blocks [0,4096) = per-batch kp (E*W*E^T -> triu/tril + E copy);
// blocks [4096,6144) = W_triu/W_tril fp32->bf16 with K-pad (2 rows each).
// Measured ~35 us vs ~41 us traffic roofline -> done.
// ---------------------------------------------------------------------------
__global__ __launch_bounds__(256) void prep_all(
    const float* __restrict__ E,        // [B,64,64]
    const float* __restrict__ Wkp,      // [64,64]
    const float* __restrict__ Wtriu,    // [4096,2080]
    const float* __restrict__ Wtril,    // [4096,2080]
    float* __restrict__ out0,           // [B,4096]
    unsigned short* __restrict__ triu,  // [B,2112] bf16
    unsigned short* __restrict__ tril,  // [B,2112] bf16
    unsigned short* __restrict__ Wu,    // [4096,2112] bf16
    unsigned short* __restrict__ Wl)    // [4096,2112] bf16
{
  const int bid = blockIdx.x;
  const int tid = threadIdx.x;

  if (bid >= 4096) {
    // ---- cvt path: 2 rows of each W matrix, coalesced float4 -> u16x4
    const int r0 = (bid - 4096) * 2;
#pragma unroll
    for (int q = 0; q < 4; ++q) {
      const int row = r0 + (q & 1);
      const float* src = (q < 2 ? Wtriu : Wtril) + (size_t)row * 2080;
      unsigned short* dst = (q < 2 ? Wu : Wl) + (size_t)row * KP;
      for (int c = tid; c < 528; c += 256) {   // u16x4 chunks per row
        u16x4 o = {0, 0, 0, 0};
        if (c < 520) {
          float4 v = *(const float4*)(src + c * 4);
          o[0] = f2bf(v.x); o[1] = f2bf(v.y); o[2] = f2bf(v.z); o[3] = f2bf(v.w);
        }
        ((u16x4*)dst)[c] = o;
      }
    }
    return;
  }

  // ---- batch path
  __shared__ __align__(16) unsigned short sE[64 * 64];
  __shared__ __align__(16) unsigned short sWt[64 * 64];  // reused as sK later
  __shared__ __align__(16) unsigned short sT[64 * 64];

  const int b = bid;
  const float* Eb = E + (size_t)b * 4096;
  float* o0 = out0 + (size_t)b * 4096;

#pragma unroll
  for (int it = 0; it < 4; ++it) {
    const int flat = it * 1024 + tid * 4;
    float4 v = *(const float4*)(Eb + flat);
    *(float4*)(o0 + flat) = v;                 // embs_flatten output (exact fp32)
    u16x4 e;
    e[0] = f2bf(v.x); e[1] = f2bf(v.y); e[2] = f2bf(v.z); e[3] = f2bf(v.w);
    *(u16x4*)(sE + flat) = e;
    float4 wv = *(const float4*)(Wkp + flat);  // inline W^T (row d, cols c0..+3)
    const int d = flat >> 6, c0 = flat & 63;
    sWt[(c0 + 0) * 64 + d] = f2bf(wv.x);
    sWt[(c0 + 1) * 64 + d] = f2bf(wv.y);
    sWt[(c0 + 2) * 64 + d] = f2bf(wv.z);
    sWt[(c0 + 3) * 64 + d] = f2bf(wv.w);
  }
  __syncthreads();

  const int lane = tid & 63, w = tid >> 6;
  const int fr = lane & 15;
  const int fk = (lane >> 4) << 3;
  const int qr = (lane >> 4) << 2;

  // T = Ebf * Wkp : wave w computes rows [w*16, w*16+16)
#pragma unroll
  for (int ct = 0; ct < 4; ++ct) {
    f32x4 acc = {0.f, 0.f, 0.f, 0.f};
#pragma unroll
    for (int k2 = 0; k2 < 2; ++k2) {
      bf16x8 a = ld_frag(sE + (w * 16 + fr) * 64 + k2 * 32 + fk);
      bf16x8 bb = ld_frag(sWt + (ct * 16 + fr) * 64 + k2 * 32 + fk);
      acc = MFMA16(a, bb, acc);
    }
#pragma unroll
    for (int r = 0; r < 4; ++r)
      sT[(w * 16 + qr + r) * 64 + ct * 16 + fr] = f2bf(acc[r]);
  }
  __syncthreads();

  // K = T * E^T ; write K (bf16) into LDS (reuse sWt)
  unsigned short* sK = sWt;
#pragma unroll
  for (int ct = 0; ct < 4; ++ct) {
    f32x4 acc = {0.f, 0.f, 0.f, 0.f};
#pragma unroll
    for (int k2 = 0; k2 < 2; ++k2) {
      bf16x8 a = ld_frag(sT + (w * 16 + fr) * 64 + k2 * 32 + fk);
      bf16x8 bb = ld_frag(sE + (ct * 16 + fr) * 64 + k2 * 32 + fk);
      acc = MFMA16(a, bb, acc);
    }
#pragma unroll
    for (int r = 0; r < 4; ++r)
      sK[(w * 16 + qr + r) * 64 + ct * 16 + fr] = f2bf(acc[r]);
  }
  __syncthreads();

  // coalesced triangular emit (16B stores, pads zeroed)
  emit_tri(sK, triu + (size_t)b * KP, true, tid);
  emit_tri(sK, tril + (size_t)b * KP, false, tid);
}

// ---------------------------------------------------------------------------
// view = A[4096,2112] @ W[4096,2112]^T, 256^2 tile, BK=64, 512 thr (2Mx4N
// waves, 128x64/wave). R9 schedule (verified), MFMA shape switched to
// 32x32x16: same ds_read counts/bytes per phase, MFMA pipe 620->516 cy/SIMD
// per tile, 128B-coalesced C stores. Phases: {gate; 8 MFMA32; post: reads
// for next phase (ping-pong) + stages; close_bar}; ONE VMWAIT(6)/tile @p3.
// Frag layout (32x32x16): A/B lane reads 8 contig bf16 @ row=lane&31,
// k=(lane>>5)*8; with the row&7 XOR swizzle each 8-lane group hits 8
// distinct 16B chunks -> conflict-free. C/D: col=lane&31,
// row=(reg&3)+8*(reg>>2)+4*(lane>>5)  [m74/m101-verified].
// ---------------------------------------------------------------------------
__global__ __launch_bounds__(512, 2) void gemm_views(
    const unsigned short* __restrict__ triu, const unsigned short* __restrict__ tril,
    const unsigned short* __restrict__ Wu, const unsigned short* __restrict__ Wl,
    float* __restrict__ dout)
{
  __shared__ __align__(16) unsigned short lds[65536];  // [2 buf][A|B][256*64]

  const int z = blockIdx.z;
  const unsigned short* Ag = z ? tril : triu;
  const unsigned short* Bg = z ? Wl : Wu;
  float* C = dout + (size_t)16777216 * (size_t)(1 + z);

  const int tid = threadIdx.x;
  const int lane = tid & 63, wv = tid >> 6;
  const int m0 = blockIdx.y << 8, n0 = blockIdx.x << 8;

  // ---- staging geometry: per cp16 a wave covers 8 rows x 64 k (1024 B linear)
  const int lr = lane >> 3;                    // row within wave's 8-row group
  const int cuch = (lane & 7) ^ lr;            // pre-swizzled global chunk
  const int rA = wv * 8 + lr;                                  // + OFF
  const int rB = (wv & 3) * 8 + (wv >> 2) * 64 + lr;           // + OFF
  const unsigned short* gA = Ag + (size_t)(m0 + rA) * KP + cuch * 8;
  const unsigned short* gB = Bg + (size_t)(n0 + rB) * KP + cuch * 8;
  const int dA = tid * 8;                                      // u16 idx
  const int dB = (wv & 3) * 512 + (wv >> 2) * 4096 + lane * 8;

  // ---- fragment-read geometry (32x32x16, swizzled)
  const int lr31 = lane & 31, hq = lane >> 5;
  const int wm = (wv >> 2) * 128, wn = (wv & 3) * 64;  // wave tile origin
  const int rowA = wm + lr31;                          // + MH*64 + mt*32
  const int rowB = wn + lr31;                          // + nt*32
  const int swz = lr31 & 7;                            // chunk ^= swz

  f32x16 acc[4][2] = {};                    // [m-subtile 0..3][n-subtile 0..1]
  bf16x8 aE_[4], aO_[4], b0_[4], b1_[4];    // ping-pong sets: [mt*2+ks]/[nt*2+ks]

#define STAGE_A(B_, KT, OFF) do { \
    cp16(gA + (size_t)(OFF) * KP + (KT) * 64, lds + (B_) * 32768 + (OFF) * 64 + dA); \
    cp16(gA + (size_t)((OFF) + 128) * KP + (KT) * 64, \
         lds + (B_) * 32768 + ((OFF) + 128) * 64 + dA); \
  } while (0)
#define STAGE_B(B_, KT, OFF) do { \
    cp16(gB + (size_t)(OFF) * KP + (KT) * 64, \
         lds + (B_) * 32768 + 16384 + (OFF) * 64 + dB); \
    cp16(gB + (size_t)((OFF) + 128) * KP + (KT) * 64, \
         lds + (B_) * 32768 + 16384 + ((OFF) + 128) * 64 + dB); \
  } while (0)
// read 4 A-frags (one 64-row M-half: 2 subtiles x 2 ksteps of the KH half)
#define LDA(S, B_, MH, KH) do { _Pragma("unroll") \
    for (int mt = 0; mt < 2; ++mt) _Pragma("unroll") \
    for (int ks = 0; ks < 2; ++ks) \
      S[mt * 2 + ks] = ld_frag(lds + (B_) * 32768 + \
          (rowA + (MH) * 64 + mt * 32) * 64 + \
          ((((KH) * 4 + ks * 2 + hq) ^ swz) * 8)); \
  } while (0)
// read 4 B-frags (2 n-subtiles x 2 ksteps of the KH half)
#define LDB(S, B_, KH) do { _Pragma("unroll") \
    for (int nt = 0; nt < 2; ++nt) _Pragma("unroll") \
    for (int ks = 0; ks < 2; ++ks) \
      S[nt * 2 + ks] = ld_frag(lds + (B_) * 32768 + 16384 + \
          (rowB + nt * 32) * 64 + \
          ((((KH) * 4 + ks * 2 + hq) ^ swz) * 8)); \
  } while (0)
#define PH_MFMA(AS, BS, MH) do { \
    __builtin_amdgcn_s_setprio(1); \
    _Pragma("unroll") for (int mt = 0; mt < 2; ++mt) \
    _Pragma("unroll") for (int nt = 0; nt < 2; ++nt) { \
      acc[(MH) * 2 + mt][nt] = MFMA32(AS[mt * 2 + 0], BS[nt * 2 + 0], acc[(MH) * 2 + mt][nt]); \
      acc[(MH) * 2 + mt][nt] = MFMA32(AS[mt * 2 + 1], BS[nt * 2 + 1], acc[(MH) * 2 + mt][nt]); } \
    __builtin_amdgcn_s_setprio(0); \
  } while (0)

  // ---- prologue: tile 0 fully + tile 1 {B0,B32,A0}; initial reads
  STAGE_A(0, 0, 0);
  STAGE_A(0, 0, 64);
  STAGE_B(0, 0, 0);
  STAGE_B(0, 0, 32);
  STAGE_B(1, 1, 0);
  STAGE_B(1, 1, 32);
  STAGE_A(1, 1, 0);
  VMWAIT(6);           // tile-0 (8 bundles) landed; tile-1 (6) in flight
  close_bar();
  LDA(aE_, 0, 0, 0);   // a[MH0,KH0](0)
  LDB(b0_, 0, 0);      // b[KH0](0)

  for (int t = 0; t < NT; ++t) {
    const int cb = t & 1, nb = cb ^ 1;
    const int t1 = (t + 1 < NT) ? t + 1 : NT - 1;   // clamp keeps vmcnt uniform
    const int t2 = (t + 2 < NT) ? t + 2 : NT - 1;   // (clamped stages unread)
    // p0: MFMA (MH0,KH0)[aE_,b0_]; post: read a[MH1,KH0]; stage SA64(nb,t+1)
    gate();
    PH_MFMA(aE_, b0_, 0);
    LDA(aO_, cb, 1, 0);
    STAGE_A(nb, t1, 64);
    close_bar();
    // p1: MFMA (MH1,KH0)[aO_,b0_]; post: read a[MH1,KH1] + b[KH1]
    gate();
    PH_MFMA(aO_, b0_, 1);
    LDA(aE_, cb, 1, 1);
    LDB(b1_, cb, 1);
    close_bar();
    // p2: MFMA (MH1,KH1)[aE_,b1_]; post: read a[MH0,KH1]; stage SB0(cb,t+2)
    gate();
    PH_MFMA(aE_, b1_, 1);
    LDA(aO_, cb, 0, 1);
    STAGE_B(cb, t2, 0);
    close_bar();
    // p3: MFMA (MH0,KH1)[aO_,b1_]; post: stage SB32+SA0(cb,t+2);
    //     VMWAIT(6) drains ALL of tile t+1's bundles; then next-tile reads
    gate();
    PH_MFMA(aO_, b1_, 0);
    STAGE_B(cb, t2, 32);
    STAGE_A(cb, t2, 0);
    VMWAIT(6);
    LDA(aE_, nb, 0, 0);
    LDB(b0_, nb, 0);
    close_bar();
  }

  // ---- epilogue: acc -> C (32x32 C/D layout; 32-lane x 4B = 128B coalesced)
#pragma unroll
  for (int mh = 0; mh < 4; ++mh) {
    const int crow = m0 + wm + mh * 32 + 4 * hq;
#pragma unroll
    for (int nt = 0; nt < 2; ++nt) {
      const int ccol = n0 + wn + nt * 32 + lr31;
      float* cp = C + (size_t)crow * 4096 + ccol;
#pragma unroll
      for (int g = 0; g < 4; ++g)
#pragma unroll
        for (int r = 0; r < 4; ++r)
          cp[(size_t)(g * 8 + r) * 4096] = acc[mh][nt][g * 4 + r];
    }
  }
#undef STAGE_A
#undef STAGE_B
#undef LDA
#undef LDB
#undef PH_MFMA
}

// ---------------------------------------------------------------------------
extern "C" void kernel_launch(void* const* d_in, const int* in_sizes, int n_in,
                              void* d_out, int out_size, void* d_ws, size_t ws_size,
                              hipStream_t stream) {
  const float* feat  = (const float*)d_in[0];   // [4096,64,64]
  const float* kpW   = (const float*)d_in[1];   // [64,64]
  const float* Wtriu = (const float*)d_in[2];   // [4096,2080]
  const float* Wtril = (const float*)d_in[3];   // [4096,2080]
  float* out = (float*)d_out;                   // [emb_flat | view1 | view2]

  // workspace layout (bf16, K-padded to 2112), ~69.2 MB
  const size_t per = (size_t)4096 * KP;
  unsigned short* triu_bf = (unsigned short*)d_ws;
  unsigned short* tril_bf = triu_bf + per;
  unsigned short* Wu_bf   = tril_bf + per;
  unsigned short* Wl_bf   = Wu_bf + per;

  prep_all<<<dim3(6144), dim3(256), 0, stream>>>(
      feat, kpW, Wtriu, Wtril, out, triu_bf, tril_bf, Wu_bf, Wl_bf);
  gemm_views<<<dim3(16, 16, 2), dim3(512), 0, stream>>>(triu_bf, tril_bf, Wu_bf, Wl_bf, out);
}